// Round 5
// baseline (194.043 us; speedup 1.0000x reference)
//
#include <hip/hip_runtime.h>
#include <hip/hip_bf16.h>

#define NROWS 16384
#define DDIM  256
#define LOG2E 1.44269504088896f

typedef __attribute__((ext_vector_type(8))) short bh8;    // 8 x bf16 (4 VGPR)
typedef __attribute__((ext_vector_type(4))) short bh4;
typedef __attribute__((ext_vector_type(4))) float fx4;
typedef __attribute__((ext_vector_type(16))) float fx16;  // 32x32 accumulator

__device__ __forceinline__ short f2bf(float x) {
  __hip_bfloat16 h = __float2bfloat16(x);
  return *reinterpret_cast<short*>(&h);
}

__device__ __forceinline__ float fexp2(float x) {
#if __has_builtin(__builtin_amdgcn_exp2f)
  return __builtin_amdgcn_exp2f(x);   // v_exp_f32: D = 2^S0
#else
  return __expf(x * 0.6931471805599453f);
#endif
}

__device__ __forceinline__ fx16 fzero16() {
  fx16 z;
#pragma unroll
  for (int q = 0; q < 16; ++q) z[q] = 0.f;
  return z;
}

template <int N>
__device__ __forceinline__ void vmw() {
  asm volatile("s_waitcnt vmcnt(%0)" ::"i"(N) : "memory");
}

// exact softplus, used only on the 16384 diagonal elements
__device__ __forceinline__ float softplus_f(float y) {
  float a = fabsf(y);
  float t = __expf(-a);
  float l;
  if (t < 0.125f) {
    l = t * (1.0f - t * (0.5f - 0.333333333f * t));
  } else {
    l = log1pf(t);
  }
  return fmaxf(y, 0.0f) + l;
}

__global__ void cast_bf16_kernel(const float* __restrict__ in,
                                 unsigned short* __restrict__ out) {
  int i = (blockIdx.x * blockDim.x + threadIdx.x) * 8;
  float4 v0 = *(const float4*)(in + i);
  float4 v1 = *(const float4*)(in + i + 4);
  bh8 o;
  o[0] = f2bf(v0.x); o[1] = f2bf(v0.y); o[2] = f2bf(v0.z); o[3] = f2bf(v0.w);
  o[4] = f2bf(v1.x); o[5] = f2bf(v1.y); o[6] = f2bf(v1.z); o[7] = f2bf(v1.w);
  *(bh8*)((unsigned short*)out + i) = o;
}

// ================= persistent strip kernel, phase-interleaved (T3+T4+T5) ===
// 256 blocks (1/CU), 512 threads = 8 waves (2 wr x 4 wc), wave tile 64x128
// via 2x4 mfma_f32_32x32x16_bf16. Block owns 128 img rows, 8192 txt cols.
// LDS: A panel 64KB frag-resident; B ring 3 x 32KB (chunk = 512 cols x K=32).
// Ring discipline: chunk t reads buf[t%3]; chunk t+2 staged into buf[(t+2)%3]
// (the buffer freed by chunk t-1) DURING chunk t's phases -> never writes the
// live read buffer; loads stay in flight across barriers (vmcnt(4), T4).
// Each chunk = 2 phases: {6 ds_read | 2 stage loads | barrier | lgkmcnt(0) |
// setprio(1) 8 MFMA setprio(0) | barrier}  (m201 template shape).

// stage half h (2 of 4 gload_lds) of chunk t into buffer bufp
#define STBH(t, bufp, h)                                                       \
  do {                                                                         \
    const int bt_ = (t) >> 3, kq_ = (t) & 7;                                   \
    const unsigned short* Bb_ =                                                \
        Bm + (size_t)(colgbase + bt_ * 512) * DDIM + kq_ * 32;                 \
    _Pragma("unroll")                                                          \
    for (int it_ = 2 * (h); it_ < 2 * (h) + 2; ++it_) {                        \
      int fb_ = it_ * 8 + wave; /* 0..31 */                                    \
      int cc_ = fb_ >> 1, ss_ = fb_ & 1;                                       \
      __builtin_amdgcn_global_load_lds(                                        \
          (const __attribute__((address_space(1))) void*)(                     \
              Bb_ + (size_t)(cc_ * 32 + (lane & 31)) * DDIM + ss_ * 16 +       \
              (lane >> 5) * 8),                                                \
          (__attribute__((address_space(3))) void*)((bufp) + it_ * 8192 +      \
                                                    wave * 1024),              \
          16, 0, 0);                                                           \
    }                                                                          \
  } while (0)

#define MFMA8(A0, A1, B0, B1, B2, B3)                                          \
  do {                                                                         \
    __builtin_amdgcn_s_setprio(1);                                             \
    acc00 = __builtin_amdgcn_mfma_f32_32x32x16_bf16(A0, B0, acc00, 0, 0, 0);   \
    acc01 = __builtin_amdgcn_mfma_f32_32x32x16_bf16(A0, B1, acc01, 0, 0, 0);   \
    acc02 = __builtin_amdgcn_mfma_f32_32x32x16_bf16(A0, B2, acc02, 0, 0, 0);   \
    acc03 = __builtin_amdgcn_mfma_f32_32x32x16_bf16(A0, B3, acc03, 0, 0, 0);   \
    acc10 = __builtin_amdgcn_mfma_f32_32x32x16_bf16(A1, B0, acc10, 0, 0, 0);   \
    acc11 = __builtin_amdgcn_mfma_f32_32x32x16_bf16(A1, B1, acc11, 0, 0, 0);   \
    acc12 = __builtin_amdgcn_mfma_f32_32x32x16_bf16(A1, B2, acc12, 0, 0, 0);   \
    acc13 = __builtin_amdgcn_mfma_f32_32x32x16_bf16(A1, B3, acc13, 0, 0, 0);   \
    __builtin_amdgcn_s_setprio(0);                                             \
  } while (0)

// one K=32 chunk = 2 phases. do_stage: stage chunk t+2 into p2.
// vmw_n: -1 = no wait, else counted vmcnt before phase-B barrier.
#define CHUNK(kq, t, do_stage, vmw_n)                                          \
  do {                                                                         \
    const char* aw_ = ldsA + wr * 32768 + (kq) * 2048 + lane * 16;             \
    const char* bw_ = p0 + wc * 8192 + lane * 16;                              \
    bh8 a0_, a1_, b0_, b1_, b2_, b3_;                                          \
    /* ---- phase A (s=0) ---- */                                              \
    a0_ = *(const bh8*)(aw_);                                                  \
    a1_ = *(const bh8*)(aw_ + 16384);                                          \
    b0_ = *(const bh8*)(bw_);                                                  \
    b1_ = *(const bh8*)(bw_ + 2048);                                           \
    b2_ = *(const bh8*)(bw_ + 4096);                                           \
    b3_ = *(const bh8*)(bw_ + 6144);                                           \
    if (do_stage) STBH((t) + 2, p2, 0);                                        \
    __builtin_amdgcn_s_barrier();                                              \
    asm volatile("s_waitcnt lgkmcnt(0)" ::: "memory");                         \
    __builtin_amdgcn_sched_barrier(0);                                         \
    MFMA8(a0_, a1_, b0_, b1_, b2_, b3_);                                       \
    __builtin_amdgcn_s_barrier();                                              \
    /* ---- phase B (s=1) ---- */                                              \
    a0_ = *(const bh8*)(aw_ + 1024);                                           \
    a1_ = *(const bh8*)(aw_ + 16384 + 1024);                                   \
    b0_ = *(const bh8*)(bw_ + 1024);                                           \
    b1_ = *(const bh8*)(bw_ + 2048 + 1024);                                    \
    b2_ = *(const bh8*)(bw_ + 4096 + 1024);                                    \
    b3_ = *(const bh8*)(bw_ + 6144 + 1024);                                    \
    if (do_stage) STBH((t) + 2, p2, 1);                                        \
    if ((vmw_n) >= 0) {                                                        \
      asm volatile("s_waitcnt vmcnt(%0)" ::"i"((vmw_n) < 0 ? 0 : (vmw_n))      \
                   : "memory");                                                \
    }                                                                          \
    __builtin_amdgcn_s_barrier();                                              \
    asm volatile("s_waitcnt lgkmcnt(0)" ::: "memory");                         \
    __builtin_amdgcn_sched_barrier(0);                                         \
    MFMA8(a0_, a1_, b0_, b1_, b2_, b3_);                                       \
    __builtin_amdgcn_s_barrier();                                              \
    char* rt_ = p0; p0 = p1; p1 = p2; p2 = rt_;                                \
  } while (0)

// per-tile epilogue for one 32x32 acc; C layout (m74/m101):
// col = lane&31, row = (reg&3) + 8*(reg>>2) + 4*(lane>>5)
#define EPI(A_, m_, n_)                                                        \
  do {                                                                         \
    fx16 v_ = A_;                                                              \
    A_ = fzero16();                                                            \
    _Pragma("unroll")                                                          \
    for (int g_ = 0; g_ < 16; g_ += 4) {                                       \
      e0 += fexp2(k1 * v_[g_ + 0]);                                            \
      e1 += fexp2(k1 * v_[g_ + 1]);                                            \
      e2 += fexp2(k1 * v_[g_ + 2]);                                            \
      e3 += fexp2(k1 * v_[g_ + 3]);                                            \
    }                                                                          \
    if (dtile) { /* block-uniform: 1 of 16 tiles */                            \
      const int gcol_ = colbase + wc * 128 + (n_) * 32 + (lane & 31);          \
      const int grow0_ = rowbase + wr * 64 + (m_) * 32 + 4 * (lane >> 5);      \
      _Pragma("unroll")                                                        \
      for (int reg_ = 0; reg_ < 16; ++reg_) {                                  \
        int grow_ = grow0_ + (reg_ & 3) + 8 * (reg_ >> 2);                     \
        if (grow_ == gcol_) {                                                  \
          d += softplus_f(-fmaf(scale, v_[reg_], bias));                       \
          e0 -= fexp2(k1 * v_[reg_]);                                          \
        }                                                                      \
      }                                                                        \
    }                                                                          \
  } while (0)

#define EPILOGUE(btv)                                                          \
  do {                                                                         \
    const int colbase = colgbase + (btv) * 512;                                \
    const bool dtile = (colbase < rowbase + 128) && (rowbase < colbase + 512); \
    EPI(acc00, 0, 0); EPI(acc01, 0, 1); EPI(acc02, 0, 2); EPI(acc03, 0, 3);    \
    EPI(acc10, 1, 0); EPI(acc11, 1, 1); EPI(acc12, 1, 2); EPI(acc13, 1, 3);    \
  } while (0)

__global__ __launch_bounds__(512, 2) void siglip_strip(
    const unsigned short* __restrict__ Am, const unsigned short* __restrict__ Bm,
    const float* __restrict__ scale_p, const float* __restrict__ bias_p,
    float* __restrict__ out) {
  extern __shared__ char smem[];
  char* ldsA = smem;            // 64KB A panel, frag-resident
  char* p0 = smem + 65536;      // B ring: 3 x 32KB
  char* p1 = smem + 98304;
  char* p2 = smem + 131072;

  const int tid  = threadIdx.x;
  const int lane = tid & 63;
  const int wave = tid >> 6;
  const int wr   = wave >> 2;  // 0..1
  const int wc   = wave & 3;   // 0..3
  const int rp   = blockIdx.x >> 1;
  const int cg   = blockIdx.x & 1;
  const int rowbase  = rp * 128;
  const int colgbase = cg * 8192;

  float scale = *scale_p;
  float bias  = *bias_p;
  asm volatile("" : "+v"(scale), "+v"(bias));
  const float k1 = scale * LOG2E;
  const float p0s = fexp2(bias * LOG2E);  // e^bias
  // drain scalar-load vmem so counted vmcnt below sees only staging loads
  asm volatile("s_waitcnt vmcnt(0)" ::: "memory");

  // ---- prologue: A panel (64 frags) + chunks 0 -> p0, 1 -> p1 ----
  {
    const unsigned short* Ab = Am + (size_t)rowbase * DDIM;
#pragma unroll
    for (int it = 0; it < 8; ++it) {
      int fa = it * 8 + wave;  // 0..63
      int r = fa >> 4, s = fa & 15;
      __builtin_amdgcn_global_load_lds(
          (const __attribute__((address_space(1))) void*)(
              Ab + (size_t)(r * 32 + (lane & 31)) * DDIM + s * 16 +
              (lane >> 5) * 8),
          (__attribute__((address_space(3))) void*)(ldsA + it * 8192 +
                                                    wave * 1024),
          16, 0, 0);
    }
  }
  STBH(0, p0, 0); STBH(0, p0, 1);
  STBH(1, p1, 0); STBH(1, p1, 1);

  fx16 acc00 = fzero16(), acc01 = fzero16(), acc02 = fzero16(),
       acc03 = fzero16();
  fx16 acc10 = fzero16(), acc11 = fzero16(), acc12 = fzero16(),
       acc13 = fzero16();
  float e0 = 0.f, e1 = 0.f, e2 = 0.f, e3 = 0.f, d = 0.f;

  // A (8) + chunk0 (4) + chunk1 (4) outstanding; wait until only chunk1's 4
  // remain -> A and chunk0 landed (in-order completion).
  vmw<4>();
  __builtin_amdgcn_s_barrier();

  for (int bt = 0; bt < 15; ++bt) {
    const int tb = bt * 8;
#pragma unroll
    for (int kq = 0; kq < 8; ++kq) {
      CHUNK(kq, tb + kq, 1, 4);
    }
    EPILOGUE(bt);  // register-only; overlaps in-flight DMA of t+1, t+2
  }

  // ---- peeled bt = 15 (chunks 120..127) ----
  {
#pragma unroll
    for (int kq = 0; kq < 8; ++kq) {
      const int t = 120 + kq;
      if (kq <= 5) {
        if (kq == 5) CHUNK(kq, t, 1, 0);   // last staged chunk is 127
        else         CHUNK(kq, t, 1, 4);
      } else {
        CHUNK(kq, t, 0, -1);               // t=126,127: no stage, no wait
      }
    }
    EPILOGUE(15);
  }

  float local = fmaf((e0 + e1) + (e2 + e3), p0s, d);
#pragma unroll
  for (int off = 32; off > 0; off >>= 1) local += __shfl_xor(local, off, 64);
  if (lane == 0) atomicAdd(out, local * (1.0f / 16384.0f));
}

// ===================== fallback: f32 inputs, reg-staged (no ws needed) =====
__device__ __forceinline__ unsigned swz256(unsigned o) {
  return o ^ (((o >> 8) & 7u) << 4);
}

__device__ __forceinline__ void map_tile(int bid, int& tr, int& tc) {
  int xcd = bid & 7;
  int idx = bid >> 3;
  int g   = idx >> 7;
  int w   = idx & 127;
  tr = xcd * 16 + (w >> 3);
  tc = g * 8 + (w & 7);
}

__global__ __launch_bounds__(256, 2) void siglip_fallback(
    const float* __restrict__ A, const float* __restrict__ B,
    const float* __restrict__ scale_p, const float* __restrict__ bias_p,
    float* __restrict__ out) {
  __shared__ char lds[65536];
  char* ldsA = lds;
  char* ldsB = lds + 32768;
  const int tid  = threadIdx.x;
  const int lane = tid & 63;
  const int wave = tid >> 6;
  const int wr   = wave >> 1;
  const int wc   = wave & 1;
  int tr, tc;
  map_tile(blockIdx.x, tr, tc);
  const int brow = tr * 128, bcol = tc * 128;

  fx4 acc[4][4];
#pragma unroll
  for (int m = 0; m < 4; ++m)
#pragma unroll
    for (int n = 0; n < 4; ++n) acc[m][n] = (fx4){0.f, 0.f, 0.f, 0.f};

#pragma unroll
  for (int p = 0; p < 2; ++p) {
    __syncthreads();
    const float* Af = A + (size_t)brow * DDIM + p * 128;
    const float* Bf = B + (size_t)bcol * DDIM + p * 128;
#pragma unroll
    for (int it = 0; it < 16; ++it) {
      int c = it * 256 + tid;
      int row = c >> 5, j = c & 31;
      unsigned o = row * 256 + j * 8;
      {
        float4 v = *(const float4*)(Af + (size_t)row * DDIM + j * 4);
        bh4 h;
        h[0] = f2bf(v.x); h[1] = f2bf(v.y); h[2] = f2bf(v.z); h[3] = f2bf(v.w);
        *(bh4*)(ldsA + swz256(o)) = h;
      }
      {
        float4 v = *(const float4*)(Bf + (size_t)row * DDIM + j * 4);
        bh4 h;
        h[0] = f2bf(v.x); h[1] = f2bf(v.y); h[2] = f2bf(v.z); h[3] = f2bf(v.w);
        *(bh4*)(ldsB + swz256(o)) = h;
      }
    }
    __syncthreads();
#pragma unroll
    for (int kk = 0; kk < 4; ++kk) {
      const int colb = kk * 64 + (lane >> 4) * 16;
      bh8 a[4], b[4];
#pragma unroll
      for (int m = 0; m < 4; ++m) {
        int r = wr * 64 + m * 16 + (lane & 15);
        a[m] = *(const bh8*)(ldsA + swz256((unsigned)(r * 256 + colb)));
      }
#pragma unroll
      for (int n = 0; n < 4; ++n) {
        int r = wc * 64 + n * 16 + (lane & 15);
        b[n] = *(const bh8*)(ldsB + swz256((unsigned)(r * 256 + colb)));
      }
#pragma unroll
      for (int m = 0; m < 4; ++m)
#pragma unroll
        for (int n = 0; n < 4; ++n)
          acc[m][n] = __builtin_amdgcn_mfma_f32_16x16x32_bf16(a[m], b[n],
                                                              acc[m][n], 0, 0, 0);
    }
  }

  const float scale = *scale_p;
  const float bias  = *bias_p;
  const float k1 = scale * LOG2E;
  const float k0 = bias * LOG2E;
  float s0 = 0.f, s1 = 0.f, s2 = 0.f, s3 = 0.f;
  const int  row0 = brow + wr * 64 + (lane >> 4) * 4;
  const int  col0 = bcol + wc * 64 + (lane & 15);
  const bool isdiag = (tr == tc);
#pragma unroll
  for (int m = 0; m < 4; ++m) {
#pragma unroll
    for (int n = 0; n < 4; ++n) {
      fx4 v = acc[m][n];
      s0 += fexp2(fmaf(k1, v[0], k0));
      s1 += fexp2(fmaf(k1, v[1], k0));
      s2 += fexp2(fmaf(k1, v[2], k0));
      s3 += fexp2(fmaf(k1, v[3], k0));
      if (isdiag) {
        const int gj = col0 + n * 16;
#pragma unroll
        for (int j = 0; j < 4; ++j) {
          const int gi = row0 + m * 16 + j;
          if (gi == gj) {
            float logit = fmaf(scale, v[j], bias);
            s0 += softplus_f(-logit) - fexp2(fmaf(k1, v[j], k0));
          }
        }
      }
    }
  }
  float local = (s0 + s1) + (s2 + s3);
#pragma unroll
  for (int off = 32; off > 0; off >>= 1) local += __shfl_xor(local, off, 64);

  __syncthreads();
  float* red = (float*)lds;
  if (lane == 0) red[wave] = local;
  __syncthreads();
  if (tid == 0)
    atomicAdd(out, (red[0] + red[1] + red[2] + red[3]) * (1.0f / 16384.0f));
}

extern "C" void kernel_launch(void* const* d_in, const int* in_sizes, int n_in,
                              void* d_out, int out_size, void* d_ws,
                              size_t ws_size, hipStream_t stream) {
  const float* img     = (const float*)d_in[0];
  const float* txt     = (const float*)d_in[1];
  const float* scale_p = (const float*)d_in[2];
  const float* bias_p  = (const float*)d_in[3];
  float* out = (float*)d_out;

  hipMemsetAsync(d_out, 0, (size_t)out_size * sizeof(float), stream);

  const size_t elems = (size_t)NROWS * DDIM;
  const size_t need  = 2 * elems * sizeof(unsigned short);  // 16.8 MB

  if (ws_size >= need) {
    hipError_t a3 = hipFuncSetAttribute(
        (const void*)siglip_strip,
        hipFuncAttributeMaxDynamicSharedMemorySize, 163840);
    if (a3 == hipSuccess) {
      unsigned short* Abf = (unsigned short*)d_ws;
      unsigned short* Bbf = Abf + elems;
      const int cast_blocks = (int)(elems / (256 * 8));  // 2048
      cast_bf16_kernel<<<cast_blocks, 256, 0, stream>>>(img, Abf);
      cast_bf16_kernel<<<cast_blocks, 256, 0, stream>>>(txt, Bbf);
      siglip_strip<<<256, 512, 163840, stream>>>(Abf, Bbf, scale_p, bias_p,
                                                 out);
      return;
    }
  }
  const int nblocks = (NROWS / 128) * (NROWS / 128);  // 16384
  siglip_fallback<<<nblocks, 256, 0, stream>>>(img, txt, scale_p, bias_p, out);
}

// Round 6
// 170.426 us; speedup vs baseline: 1.1386x; 1.1386x over previous
//
#include <hip/hip_runtime.h>
#include <hip/hip_bf16.h>

#define NROWS 16384
#define DDIM  256
#define LOG2E 1.44269504088896f

typedef __attribute__((ext_vector_type(8))) short bh8;   // 8 x bf16 (4 VGPR)
typedef __attribute__((ext_vector_type(4))) short bh4;
typedef __attribute__((ext_vector_type(4))) float fx4;

__device__ __forceinline__ short f2bf(float x) {
  __hip_bfloat16 h = __float2bfloat16(x);
  return *reinterpret_cast<short*>(&h);
}

__device__ __forceinline__ float fexp2(float x) {
#if __has_builtin(__builtin_amdgcn_exp2f)
  return __builtin_amdgcn_exp2f(x);   // v_exp_f32: D = 2^S0
#else
  return __expf(x * 0.6931471805599453f);
#endif
}

// exact softplus, used only on the 16384 diagonal elements
__device__ __forceinline__ float softplus_f(float y) {
  float a = fabsf(y);
  float t = __expf(-a);
  float l;
  if (t < 0.125f) {
    l = t * (1.0f - t * (0.5f - 0.333333333f * t));
  } else {
    l = log1pf(t);
  }
  return fmaxf(y, 0.0f) + l;
}

__global__ void cast_bf16_kernel(const float* __restrict__ in,
                                 unsigned short* __restrict__ out) {
  int i = (blockIdx.x * blockDim.x + threadIdx.x) * 8;
  float4 v0 = *(const float4*)(in + i);
  float4 v1 = *(const float4*)(in + i + 4);
  bh8 o;
  o[0] = f2bf(v0.x); o[1] = f2bf(v0.y); o[2] = f2bf(v0.z); o[3] = f2bf(v0.w);
  o[4] = f2bf(v1.x); o[5] = f2bf(v1.y); o[6] = f2bf(v1.z); o[7] = f2bf(v1.w);
  *(bh8*)((unsigned short*)out + i) = o;
}

// ================= persistent strip kernel =================================
// 256 blocks (1/CU), 512 threads = 8 waves (2 wr x 4 wc), wave tile 64x64 of
// 16x16x32 MFMA (4x4 fx4 accs). Block owns 128 img rows x 8192 txt cols.
// LDS 160KB: A panel 64KB frag-resident (wave-linear reads, conflict-free);
// B ring 3 x 32KB, chunk = 256 cols x 64 k, content o = col*128+kb stored at
// p = o ^ ((o>>7)&7)<<4 (involution). Staging source is 128B-contiguous per
// col (coalesced, no L2 overfetch); reads spread 8-per-bank-quad (ideal).
// Chunk = 2 phases: {4A+4B ds_read | 2 stage | bar | lgkm0 | 16 MFMA | bar},
// ring chunk t reads q0 while t+2 stages into q2; vmcnt(4) once per chunk.

// stage half h (2 of 4 gload_lds) of chunk (bt2,kc2) into buffer bufp
#define STB(bt2, kc2, bufp, h)                                                 \
  do {                                                                         \
    _Pragma("unroll")                                                          \
    for (int it_ = 2 * (h); it_ < 2 * (h) + 2; ++it_) {                        \
      __builtin_amdgcn_global_load_lds(                                        \
          (const __attribute__((address_space(1))) void*)(                     \
              Bm + (size_t)(colgbase + (bt2) * 256 + it_ * 64 + colL) * DDIM + \
              (kc2) * 64 + kelemL),                                            \
          (__attribute__((address_space(3))) void*)((bufp) + it_ * 8192 +      \
                                                    wave * 1024 + lane * 16),  \
          16, 0, 0);                                                           \
    }                                                                          \
  } while (0)

#define MFMA16()                                                               \
  do {                                                                         \
    __builtin_amdgcn_s_setprio(1);                                             \
    _Pragma("unroll")                                                          \
    for (int m_ = 0; m_ < 4; ++m_) {                                           \
      acc[m_][0] = __builtin_amdgcn_mfma_f32_16x16x32_bf16(av[m_], bv[0],      \
                                                           acc[m_][0], 0,0,0); \
      acc[m_][1] = __builtin_amdgcn_mfma_f32_16x16x32_bf16(av[m_], bv[1],      \
                                                           acc[m_][1], 0,0,0); \
      acc[m_][2] = __builtin_amdgcn_mfma_f32_16x16x32_bf16(av[m_], bv[2],      \
                                                           acc[m_][2], 0,0,0); \
      acc[m_][3] = __builtin_amdgcn_mfma_f32_16x16x32_bf16(av[m_], bv[3],      \
                                                           acc[m_][3], 0,0,0); \
    }                                                                          \
    __builtin_amdgcn_s_setprio(0);                                             \
  } while (0)

// one phase: kpage = kc*2+s (A k-page), Xs = swizzled B k-offset for s
#define PHASE(kpage, Xs, DO_ST, BT2, KC2, SH, WN)                              \
  do {                                                                         \
    bh8 av[4], bv[4];                                                          \
    {                                                                          \
      const char* aP_ = ldsA + (size_t)((wr * 32 + (kpage)) * 1024) +          \
                        lane * 16;                                             \
      av[0] = *(const bh8*)(aP_);                                              \
      av[1] = *(const bh8*)(aP_ + 8192);                                       \
      av[2] = *(const bh8*)(aP_ + 16384);                                      \
      av[3] = *(const bh8*)(aP_ + 24576);                                      \
      const char* bP_ = q0 + bb + (Xs);                                        \
      bv[0] = *(const bh8*)(bP_);                                              \
      bv[1] = *(const bh8*)(bP_ + 2048);                                       \
      bv[2] = *(const bh8*)(bP_ + 4096);                                       \
      bv[3] = *(const bh8*)(bP_ + 6144);                                       \
    }                                                                          \
    if (DO_ST) STB(BT2, KC2, q2, SH);                                          \
    __builtin_amdgcn_s_barrier();                                              \
    asm volatile("s_waitcnt lgkmcnt(0)" ::: "memory");                         \
    __builtin_amdgcn_sched_barrier(0);                                         \
    MFMA16();                                                                  \
    if ((WN) >= 0)                                                             \
      asm volatile("s_waitcnt vmcnt(%0)" ::"i"((WN) < 0 ? 0 : (WN))            \
                   : "memory");                                                \
    __builtin_amdgcn_s_barrier();                                              \
  } while (0)

// one K=64 chunk (2 phases) + ring rotation
#define CHUNK(kc, DO_ST, BT2, KC2, WN)                                         \
  do {                                                                         \
    PHASE((kc) * 2 + 0, X0, DO_ST, BT2, KC2, 0, -1);                           \
    PHASE((kc) * 2 + 1, X1, DO_ST, BT2, KC2, 1, WN);                           \
    char* rt_ = q0; q0 = q1; q1 = q2; q2 = rt_;                                \
  } while (0)

// per-tile epilogue; 16x16 C layout (m89): col=lane&15, row=(lane>>4)*4+j
#define EPI(m_, n_)                                                            \
  do {                                                                         \
    fx4 v_ = acc[m_][n_];                                                      \
    acc[m_][n_] = (fx4){0.f, 0.f, 0.f, 0.f};                                   \
    e0 += fexp2(k1 * v_[0]);                                                   \
    e1 += fexp2(k1 * v_[1]);                                                   \
    e2 += fexp2(k1 * v_[2]);                                                   \
    e3 += fexp2(k1 * v_[3]);                                                   \
    if (dtile) {                                                               \
      const int gj_ = colbase + wc * 64 + (n_) * 16 + (lane & 15);             \
      _Pragma("unroll")                                                        \
      for (int j_ = 0; j_ < 4; ++j_) {                                         \
        const int gi_ = rowbase + wr * 64 + (m_) * 16 + (lane >> 4) * 4 + j_;  \
        if (gi_ == gj_) {                                                      \
          d += softplus_f(-fmaf(scale, v_[j_], bias));                         \
          e0 -= fexp2(k1 * v_[j_]);                                            \
        }                                                                      \
      }                                                                        \
    }                                                                          \
  } while (0)

#define EPILOGUE(btv)                                                          \
  do {                                                                         \
    const int colbase = colgbase + (btv) * 256;                                \
    const bool dtile =                                                         \
        (colbase < rowbase + 128) && (rowbase < colbase + 256);                \
    _Pragma("unroll")                                                          \
    for (int m_ = 0; m_ < 4; ++m_) {                                           \
      EPI(m_, 0); EPI(m_, 1); EPI(m_, 2); EPI(m_, 3);                          \
    }                                                                          \
  } while (0)

__global__ __launch_bounds__(512, 2) void siglip_strip(
    const unsigned short* __restrict__ Am, const unsigned short* __restrict__ Bm,
    const float* __restrict__ scale_p, const float* __restrict__ bias_p,
    float* __restrict__ out) {
  extern __shared__ char smem[];
  char* ldsA = smem;           // 64KB A panel, frag-resident
  char* q0 = smem + 65536;     // B ring: 3 x 32KB
  char* q1 = smem + 98304;
  char* q2 = smem + 131072;

  const int tid  = threadIdx.x;
  const int lane = tid & 63;
  const int wave = tid >> 6;
  const int wr   = wave >> 2;  // 0..1
  const int wc   = wave & 3;   // 0..3
  const int rp   = blockIdx.x >> 1;
  const int cg   = blockIdx.x & 1;
  const int rowbase  = rp * 128;
  const int colgbase = cg * 8192;

  // ---- per-lane staging/read constants ----
  // stage: linear dest slot l*16 holds content o = (l*16) ^ ((l>>3)&7)<<4
  const int colL   = wave * 8 + (lane >> 3);                       // 0..63
  const int kelemL = (((lane & 7) * 16) ^ (((lane >> 3) & 7) << 4)) >> 1;
  // read: col = wc*64 + n*16 + (lane&15); swizzle ((col&7)=(lane&7))<<4
  const int bb = (wc * 64 + (lane & 15)) * 128;
  const int X0 = ((lane >> 4) * 16) ^ ((lane & 7) << 4);           // s=0
  const int X1 = X0 ^ 64;                                          // s=1

  float scale = *scale_p;
  float bias  = *bias_p;
  asm volatile("" : "+v"(scale), "+v"(bias));
  const float k1 = scale * LOG2E;
  const float eb = fexp2(bias * LOG2E);  // e^bias
  // drain scalar-load vmem so counted vmcnt sees only staging loads
  asm volatile("s_waitcnt vmcnt(0)" ::: "memory");

  // ---- prologue: A panel (8 instr/wave, 64B-contiguous per 16 rows) ----
  {
    const unsigned short* Ab = Am + (size_t)rowbase * DDIM;
#pragma unroll
    for (int it = 0; it < 8; ++it) {
      __builtin_amdgcn_global_load_lds(
          (const __attribute__((address_space(1))) void*)(
              Ab + (size_t)(it * 16 + (lane & 15)) * DDIM + wave * 32 +
              (lane >> 4) * 8),
          (__attribute__((address_space(3))) void*)(
              ldsA + (it * 8 + wave) * 1024 + lane * 16),
          16, 0, 0);
    }
  }
  STB(0, 0, q0, 0); STB(0, 0, q0, 1);   // chunk 0
  STB(0, 1, q1, 0); STB(0, 1, q1, 1);   // chunk 1

  fx4 acc[4][4];
#pragma unroll
  for (int m = 0; m < 4; ++m)
#pragma unroll
    for (int n = 0; n < 4; ++n) acc[m][n] = (fx4){0.f, 0.f, 0.f, 0.f};
  float e0 = 0.f, e1 = 0.f, e2 = 0.f, e3 = 0.f, d = 0.f;

  // A(8) + chunk0(4) + chunk1(4) outstanding; leave chunk1's 4 in flight
  asm volatile("s_waitcnt vmcnt(4)" ::: "memory");
  __builtin_amdgcn_s_barrier();

  for (int bt = 0; bt < 31; ++bt) {
    CHUNK(0, 1, bt, 2, 4);
    CHUNK(1, 1, bt, 3, 4);
    CHUNK(2, 1, bt + 1, 0, 4);
    CHUNK(3, 1, bt + 1, 1, 4);
    EPILOGUE(bt);  // register-only; t+1/t+2 DMA stays in flight
  }
  // ---- peeled bt = 31 (chunks 124..127) ----
  {
    CHUNK(0, 1, 31, 2, 4);
    CHUNK(1, 1, 31, 3, 4);
    CHUNK(2, 0, 0, 0, 0);    // wait for chunk 127 (last outstanding)
    CHUNK(3, 0, 0, 0, -1);
    EPILOGUE(31);
  }

  float local = fmaf((e0 + e1) + (e2 + e3), eb, d);
#pragma unroll
  for (int off = 32; off > 0; off >>= 1) local += __shfl_xor(local, off, 64);
  if (lane == 0) atomicAdd(out, local * (1.0f / 16384.0f));
}

// ===================== fallback: f32 inputs, reg-staged (no ws needed) =====
__device__ __forceinline__ unsigned swz256(unsigned o) {
  return o ^ (((o >> 8) & 7u) << 4);
}

__device__ __forceinline__ void map_tile(int bid, int& tr, int& tc) {
  int xcd = bid & 7;
  int idx = bid >> 3;
  int g   = idx >> 7;
  int w   = idx & 127;
  tr = xcd * 16 + (w >> 3);
  tc = g * 8 + (w & 7);
}

__global__ __launch_bounds__(256, 2) void siglip_fallback(
    const float* __restrict__ A, const float* __restrict__ B,
    const float* __restrict__ scale_p, const float* __restrict__ bias_p,
    float* __restrict__ out) {
  __shared__ char lds[65536];
  char* ldsA = lds;
  char* ldsB = lds + 32768;
  const int tid  = threadIdx.x;
  const int lane = tid & 63;
  const int wave = tid >> 6;
  const int wr   = wave >> 1;
  const int wc   = wave & 1;
  int tr, tc;
  map_tile(blockIdx.x, tr, tc);
  const int brow = tr * 128, bcol = tc * 128;

  fx4 acc[4][4];
#pragma unroll
  for (int m = 0; m < 4; ++m)
#pragma unroll
    for (int n = 0; n < 4; ++n) acc[m][n] = (fx4){0.f, 0.f, 0.f, 0.f};

#pragma unroll
  for (int p = 0; p < 2; ++p) {
    __syncthreads();
    const float* Af = A + (size_t)brow * DDIM + p * 128;
    const float* Bf = B + (size_t)bcol * DDIM + p * 128;
#pragma unroll
    for (int it = 0; it < 16; ++it) {
      int c = it * 256 + tid;
      int row = c >> 5, j = c & 31;
      unsigned o = row * 256 + j * 8;
      {
        float4 v = *(const float4*)(Af + (size_t)row * DDIM + j * 4);
        bh4 h;
        h[0] = f2bf(v.x); h[1] = f2bf(v.y); h[2] = f2bf(v.z); h[3] = f2bf(v.w);
        *(bh4*)(ldsA + swz256(o)) = h;
      }
      {
        float4 v = *(const float4*)(Bf + (size_t)row * DDIM + j * 4);
        bh4 h;
        h[0] = f2bf(v.x); h[1] = f2bf(v.y); h[2] = f2bf(v.z); h[3] = f2bf(v.w);
        *(bh4*)(ldsB + swz256(o)) = h;
      }
    }
    __syncthreads();
#pragma unroll
    for (int kk = 0; kk < 4; ++kk) {
      const int colb = kk * 64 + (lane >> 4) * 16;
      bh8 a[4], b[4];
#pragma unroll
      for (int m = 0; m < 4; ++m) {
        int r = wr * 64 + m * 16 + (lane & 15);
        a[m] = *(const bh8*)(ldsA + swz256((unsigned)(r * 256 + colb)));
      }
#pragma unroll
      for (int n = 0; n < 4; ++n) {
        int r = wc * 64 + n * 16 + (lane & 15);
        b[n] = *(const bh8*)(ldsB + swz256((unsigned)(r * 256 + colb)));
      }
#pragma unroll
      for (int m = 0; m < 4; ++m)
#pragma unroll
        for (int n = 0; n < 4; ++n)
          acc[m][n] = __builtin_amdgcn_mfma_f32_16x16x32_bf16(a[m], b[n],
                                                              acc[m][n], 0, 0, 0);
    }
  }

  const float scale = *scale_p;
  const float bias  = *bias_p;
  const float k1 = scale * LOG2E;
  const float k0 = bias * LOG2E;
  float s0 = 0.f, s1 = 0.f, s2 = 0.f, s3 = 0.f;
  const int  row0 = brow + wr * 64 + (lane >> 4) * 4;
  const int  col0 = bcol + wc * 64 + (lane & 15);
  const bool isdiag = (tr == tc);
#pragma unroll
  for (int m = 0; m < 4; ++m) {
#pragma unroll
    for (int n = 0; n < 4; ++n) {
      fx4 v = acc[m][n];
      s0 += fexp2(fmaf(k1, v[0], k0));
      s1 += fexp2(fmaf(k1, v[1], k0));
      s2 += fexp2(fmaf(k1, v[2], k0));
      s3 += fexp2(fmaf(k1, v[3], k0));
      if (isdiag) {
        const int gj = col0 + n * 16;
#pragma unroll
        for (int j = 0; j < 4; ++j) {
          const int gi = row0 + m * 16 + j;
          if (gi == gj) {
            float logit = fmaf(scale, v[j], bias);
            s0 += softplus_f(-logit) - fexp2(fmaf(k1, v[j], k0));
          }
        }
      }
    }
  }
  float local = (s0 + s1) + (s2 + s3);
#pragma unroll
  for (int off = 32; off > 0; off >>= 1) local += __shfl_xor(local, off, 64);

  __syncthreads();
  float* red = (float*)lds;
  if (lane == 0) red[wave] = local;
  __syncthreads();
  if (tid == 0)
    atomicAdd(out, (red[0] + red[1] + red[2] + red[3]) * (1.0f / 16384.0f));
}

extern "C" void kernel_launch(void* const* d_in, const int* in_sizes, int n_in,
                              void* d_out, int out_size, void* d_ws,
                              size_t ws_size, hipStream_t stream) {
  const float* img     = (const float*)d_in[0];
  const float* txt     = (const float*)d_in[1];
  const float* scale_p = (const float*)d_in[2];
  const float* bias_p  = (const float*)d_in[3];
  float* out = (float*)d_out;

  hipMemsetAsync(d_out, 0, (size_t)out_size * sizeof(float), stream);

  const size_t elems = (size_t)NROWS * DDIM;
  const size_t need  = 2 * elems * sizeof(unsigned short);  // 16.8 MB

  if (ws_size >= need) {
    hipError_t a3 = hipFuncSetAttribute(
        (const void*)siglip_strip,
        hipFuncAttributeMaxDynamicSharedMemorySize, 163840);
    if (a3 == hipSuccess) {
      unsigned short* Abf = (unsigned short*)d_ws;
      unsigned short* Bbf = Abf + elems;
      const int cast_blocks = (int)(elems / (256 * 8));  // 2048
      cast_bf16_kernel<<<cast_blocks, 256, 0, stream>>>(img, Abf);
      cast_bf16_kernel<<<cast_blocks, 256, 0, stream>>>(txt, Bbf);
      siglip_strip<<<256, 512, 163840, stream>>>(Abf, Bbf, scale_p, bias_p,
                                                 out);
      return;
    }
  }
  const int nblocks = (NROWS / 128) * (NROWS / 128);  // 16384
  siglip_fallback<<<nblocks, 256, 0, stream>>>(img, txt, scale_p, bias_p, out);
}